// Round 1
// baseline (286.928 us; speedup 1.0000x reference)
//
#include <hip/hip_runtime.h>

#define LN_EPS 1e-5f

// Kernel 1: per-batch  o[b] = (LN(act[b]) @ vw + vb) @ ow + ob
// 32 blocks (one per batch), 256 threads (one per channel).
__global__ __launch_bounds__(256) void compute_o_kernel(
    const float* __restrict__ act,   // [32,256]
    const float* __restrict__ ln_w,  // [256]
    const float* __restrict__ ln_b,  // [256]
    const float* __restrict__ vw,    // [256,256] row-major [a][c]
    const float* __restrict__ vb,    // [256]
    const float* __restrict__ ow,    // [256,256] row-major [j][c]
    const float* __restrict__ ob,    // [256]
    float* __restrict__ o)           // [32,256]
{
    const int b = blockIdx.x;
    const int t = threadIdx.x;
    __shared__ float sa[256];
    __shared__ float sv[256];

    sa[t] = act[b * 256 + t];
    __syncthreads();

    // mean / variance over 256 elements (LDS broadcast reads — conflict-free)
    float sum = 0.f;
    #pragma unroll 8
    for (int j = 0; j < 256; ++j) sum += sa[j];
    const float mu = sum * (1.0f / 256.0f);
    float vs = 0.f;
    #pragma unroll 8
    for (int j = 0; j < 256; ++j) { float d = sa[j] - mu; vs += d * d; }
    const float inv = rsqrtf(vs * (1.0f / 256.0f) + LN_EPS);

    const float an = (sa[t] - mu) * inv * ln_w[t] + ln_b[t];
    __syncthreads();          // everyone done reading raw sa
    sa[t] = an;               // reuse as normalized act
    __syncthreads();

    // v[t] = sum_a an[a] * vw[a][t] + vb[t]   (coalesced column reads)
    float v = vb[t];
    #pragma unroll 8
    for (int a = 0; a < 256; ++a) v += sa[a] * vw[a * 256 + t];
    sv[t] = v;
    __syncthreads();

    // o[t] = sum_j v[j] * ow[j][t] + ob[t]
    float oo = ob[t];
    #pragma unroll 8
    for (int j = 0; j < 256; ++j) oo += sv[j] * ow[j * 256 + t];
    o[b * 256 + t] = oo;
}

// Kernel 2: out[b,c,:,:] = img[b,c,:,:] + o[b,c]
// One block per (b,c) plane of 64*64 = 4096 floats; float4 vectorized.
__global__ __launch_bounds__(256) void residual_add_kernel(
    const float* __restrict__ img,
    const float* __restrict__ o,
    float* __restrict__ out)
{
    const int bc = blockIdx.x;        // 0..8191  (= b*256 + c)
    const int t  = threadIdx.x;
    const float ov = o[bc];
    const float4* __restrict__ img4 = (const float4*)(img + (size_t)bc * 4096);
    float4* __restrict__ out4       = (float4*)(out + (size_t)bc * 4096);
    #pragma unroll
    for (int i = 0; i < 4; ++i) {
        float4 x = img4[t + 256 * i];
        x.x += ov; x.y += ov; x.z += ov; x.w += ov;
        out4[t + 256 * i] = x;
    }
}

extern "C" void kernel_launch(void* const* d_in, const int* in_sizes, int n_in,
                              void* d_out, int out_size, void* d_ws, size_t ws_size,
                              hipStream_t stream) {
    // Input order: img, act, gn_w, gn_b, ln_w, ln_b, qw, qb, kw, kb, vw, vb, ow, ob
    const float* img  = (const float*)d_in[0];
    const float* act  = (const float*)d_in[1];
    const float* ln_w = (const float*)d_in[4];
    const float* ln_b = (const float*)d_in[5];
    const float* vw   = (const float*)d_in[10];
    const float* vb   = (const float*)d_in[11];
    const float* ow   = (const float*)d_in[12];
    const float* ob   = (const float*)d_in[13];
    float* out = (float*)d_out;
    float* o   = (float*)d_ws;   // 32*256 floats = 32 KB scratch

    compute_o_kernel<<<32, 256, 0, stream>>>(act, ln_w, ln_b, vw, vb, ow, ob, o);
    residual_add_kernel<<<8192, 256, 0, stream>>>(img, o, out);
}

// Round 2
// 257.501 us; speedup vs baseline: 1.1143x; 1.1143x over previous
//
#include <hip/hip_runtime.h>

#define LN_EPS 1e-5f

typedef float vfloat4 __attribute__((ext_vector_type(4)));

// Kernel 1: per-batch  o[b] = (LN(act[b]) @ vw + vb) @ ow + ob
// 32 blocks (one per batch), 1024 threads: 4 reduction slices x 256 columns.
__global__ __launch_bounds__(1024) void compute_o_kernel(
    const float* __restrict__ act,   // [32,256]
    const float* __restrict__ ln_w,  // [256]
    const float* __restrict__ ln_b,  // [256]
    const float* __restrict__ vw,    // [256,256] row-major [a][c]
    const float* __restrict__ vb,    // [256]
    const float* __restrict__ ow,    // [256,256] row-major [j][c]
    const float* __restrict__ ob,    // [256]
    float* __restrict__ o)           // [32,256]
{
    const int b = blockIdx.x;
    const int t = threadIdx.x;   // 0..1023
    const int c = t & 255;       // output column
    const int s = t >> 8;        // reduction slice 0..3

    __shared__ float sa[256];    // act row, then normalized act
    __shared__ float sv[256];    // v vector
    __shared__ float red[1024];  // cross-slice partials
    __shared__ float stats[2];   // mu, inv_sigma

    if (t < 256) sa[t] = act[b * 256 + t];
    __syncthreads();

    // LayerNorm stats: sum & sumsq over 256 elems via wave shuffles (4 waves)
    if (t < 256) {
        float x = sa[t];
        float sum = x, sq = x * x;
        #pragma unroll
        for (int off = 32; off > 0; off >>= 1) {
            sum += __shfl_xor(sum, off, 64);
            sq  += __shfl_xor(sq,  off, 64);
        }
        if ((t & 63) == 0) { red[t >> 6] = sum; red[4 + (t >> 6)] = sq; }
    }
    __syncthreads();
    if (t == 0) {
        float sum = red[0] + red[1] + red[2] + red[3];
        float sq  = red[4] + red[5] + red[6] + red[7];
        float mu  = sum * (1.0f / 256.0f);
        float var = sq * (1.0f / 256.0f) - mu * mu;
        stats[0] = mu;
        stats[1] = rsqrtf(var + LN_EPS);
    }
    __syncthreads();
    if (t < 256) {
        sa[t] = (sa[t] - stats[0]) * stats[1] * ln_w[t] + ln_b[t];
    }
    __syncthreads();

    // GEMV1: v[c] = vb[c] + sum_a an[a] * vw[a][c], split over 4 slices
    const int a0 = s * 64;
    float acc = 0.f;
    #pragma unroll 8
    for (int i = 0; i < 64; ++i) {
        const int a = a0 + i;
        acc += sa[a] * vw[a * 256 + c];   // sa[a]: LDS broadcast; vw: coalesced
    }
    red[t] = acc;
    __syncthreads();
    if (t < 256) {
        sv[t] = vb[t] + red[t] + red[t + 256] + red[t + 512] + red[t + 768];
    }
    __syncthreads();

    // GEMV2: o[c] = ob[c] + sum_j v[j] * ow[j][c]
    float acc2 = 0.f;
    #pragma unroll 8
    for (int i = 0; i < 64; ++i) {
        const int j = a0 + i;
        acc2 += sv[j] * ow[j * 256 + c];
    }
    red[t] = acc2;
    __syncthreads();
    if (t < 256) {
        o[b * 256 + t] = ob[t] + red[t] + red[t + 256] + red[t + 512] + red[t + 768];
    }
}

// Kernel 2: out[b,c,:,:] = img[b,c,:,:] + o[b,c]
// One block per (b,c) plane of 64*64 = 4096 floats; nontemporal float4 stream.
__global__ __launch_bounds__(256) void residual_add_kernel(
    const float* __restrict__ img,
    const float* __restrict__ o,
    float* __restrict__ out)
{
    const int bc = blockIdx.x;        // 0..8191  (= b*256 + c)
    const int t  = threadIdx.x;
    const float ov = o[bc];
    const vfloat4* __restrict__ img4 = (const vfloat4*)(img + (size_t)bc * 4096);
    vfloat4* __restrict__ out4       = (vfloat4*)(out + (size_t)bc * 4096);
    #pragma unroll
    for (int i = 0; i < 4; ++i) {
        vfloat4 x = __builtin_nontemporal_load(img4 + t + 256 * i);
        x += ov;
        __builtin_nontemporal_store(x, out4 + t + 256 * i);
    }
}

extern "C" void kernel_launch(void* const* d_in, const int* in_sizes, int n_in,
                              void* d_out, int out_size, void* d_ws, size_t ws_size,
                              hipStream_t stream) {
    // Input order: img, act, gn_w, gn_b, ln_w, ln_b, qw, qb, kw, kb, vw, vb, ow, ob
    const float* img  = (const float*)d_in[0];
    const float* act  = (const float*)d_in[1];
    const float* ln_w = (const float*)d_in[4];
    const float* ln_b = (const float*)d_in[5];
    const float* vw   = (const float*)d_in[10];
    const float* vb   = (const float*)d_in[11];
    const float* ow   = (const float*)d_in[12];
    const float* ob   = (const float*)d_in[13];
    float* out = (float*)d_out;
    float* o   = (float*)d_ws;   // 32*256 floats = 32 KB scratch

    compute_o_kernel<<<32, 1024, 0, stream>>>(act, ln_w, ln_b, vw, vb, ow, ob, o);
    residual_add_kernel<<<8192, 256, 0, stream>>>(img, o, out);
}